// Round 8
// baseline (707.019 us; speedup 1.0000x reference)
//
#include <hip/hip_runtime.h>

typedef _Float16 f16;
typedef __attribute__((ext_vector_type(4))) _Float16 f16x4;
typedef __attribute__((ext_vector_type(8))) _Float16 f16x8;
typedef __attribute__((ext_vector_type(4))) float f32x4;

#define MFMA16(a, b, c) __builtin_amdgcn_mfma_f32_16x16x32_f16(a, b, c, 0, 0, 0)

__device__ __forceinline__ void gll16(const void* g, void* l) {
    __builtin_amdgcn_global_load_lds(
        (const __attribute__((address_space(1))) unsigned int*)g,
        (__attribute__((address_space(3))) unsigned int*)l, 16, 0, 0);
}

#define BAR() __builtin_amdgcn_s_barrier()
#define LGKM(n) do { asm volatile("s_waitcnt lgkmcnt(" #n ")" ::: "memory"); \
                     __builtin_amdgcn_sched_barrier(0); } while (0)
#define VMC(n)  do { asm volatile("s_waitcnt vmcnt(" #n ")" ::: "memory"); \
                     __builtin_amdgcn_sched_barrier(0); } while (0)

// ---------------------------------------------------------------------------
// fp32 -> f16 convert
// ---------------------------------------------------------------------------
__global__ __launch_bounds__(256) void cvt_f16(
    const float* __restrict__ in, f16* __restrict__ out)
{
    const size_t i = ((size_t)blockIdx.x * 256 + threadIdx.x) * 8;
    float4 a = *(const float4*)(in + i);
    float4 b = *(const float4*)(in + i + 4);
    f16x8 o;
    o[0] = (f16)a.x; o[1] = (f16)a.y; o[2] = (f16)a.z; o[3] = (f16)a.w;
    o[4] = (f16)b.x; o[5] = (f16)b.y; o[6] = (f16)b.z; o[7] = (f16)b.w;
    *(f16x8*)(out + i) = o;
}

// ---------------------------------------------------------------------------
// Weight prep: W fp32 [K=1024][N=1024] -> Wt f16 [N][K]
// ---------------------------------------------------------------------------
__global__ __launch_bounds__(256) void prep_weights(
    const float* __restrict__ Wq, const float* __restrict__ Wk,
    const float* __restrict__ Wv, f16* __restrict__ Wt)
{
    __shared__ float tile[32][33];
    const float* W = blockIdx.z == 0 ? Wq : (blockIdx.z == 1 ? Wk : Wv);
    f16* dst = Wt + (size_t)blockIdx.z * 1024 * 1024;
    const int tx = threadIdx.x & 31, ty = threadIdx.x >> 5;
    const int n0 = blockIdx.x * 32, k0 = blockIdx.y * 32;
#pragma unroll
    for (int i = 0; i < 4; i++)
        tile[ty + i * 8][tx] = W[(size_t)(k0 + ty + i * 8) * 1024 + n0 + tx];
    __syncthreads();
#pragma unroll
    for (int i = 0; i < 4; i++)
        dst[(size_t)(n0 + ty + i * 8) * 1024 + k0 + tx] = (f16)tile[tx][ty + i * 8];
}

// ---------------------------------------------------------------------------
// 256x256 GEMM, m201-faithful 8-phase/2-tile schedule:
// one half-matrix stage (2 gll) per phase, stream 5-phases-ahead-of-need;
// ONE vmcnt(6) gate per K-tile at phi4 (gated half issued 3-6 phases prior;
// steady state: 3 halves in flight after each gate). Prologue vmcnt(4)+vmcnt(6);
// last two tiles peeled (vmcnt(0) at phi4(NT-2); bare final tile).
// EPI: 0 = bias+scale -> f16 (Q proj)
//      1 = fused K|V proj: cols<1024 -> C0 (Kh), cols>=1024 -> C1 transposed (Vt)
//      2 = exp -> f16 S + per-row partial sums -> aux (QK^T)
//      3 = multiply by aux[row] -> f32 (PV)
// ---------------------------------------------------------------------------
template <int KD, int EPI>
__global__ __launch_bounds__(512, 2) void gemm8(
    const f16* __restrict__ Ab, const f16* __restrict__ Bb,
    const float* __restrict__ b0, const float* __restrict__ b1, float scale,
    void* __restrict__ C0, void* __restrict__ C1, float* __restrict__ aux,
    size_t strA, size_t strB, size_t strC, int ldc, int nbx, int nby)
{
    __shared__ f16 shA[2][256 * 64];
    __shared__ f16 shB[2][256 * 64];

    int id = blockIdx.x;
    {
        const int chunk = (int)gridDim.x >> 3;
        id = (id & 7) * chunk + (id >> 3);
    }
    const int by = id % nby;
    const int r2 = id / nby;
    const int bx = r2 % nbx;
    const int z  = r2 / nbx;
    const int bm = bx * 256, bn = by * 256;

    const f16* A = Ab + (size_t)z * strA;
    const f16* B = Bb + (size_t)z * strB;

    const int t = threadIdx.x, lane = t & 63, wid = t >> 6;
    const int wr = wid >> 2, wc = wid & 3;
    const int fr = lane & 15, kb = (lane >> 4) * 16;
    const int sw = (fr & 7) << 4;

    const int lsr = lane >> 3;
    const int lsc = ((lane & 7) * 16) ^ (lsr << 4);
    const int a_  = wid * 8;
    const int bq_ = (wid >> 2) * 64 + (wid & 3) * 8;
    const f16* aT = A + (size_t)(bm + lsr) * KD + (lsc >> 1);
    const f16* bT = B + (size_t)(bn + lsr) * KD + (lsc >> 1);

// half-matrix stage units (2 glls each). Row coverage matched to fragment
// needs: A0 = rows {0-63,128-191} (af0 for wr=0/1), A1 = {64-127,192-255},
// B0 = nh=0 rows {0-31,64-95,128-159,192-223}, B1 = +32.
#define STG_A0(d, kt) do {                                                    \
        const f16* As_ = aT + (size_t)(kt) * 64; f16* da_ = &shA[d][0];       \
        gll16(As_ + (size_t)(a_)*KD,        da_ + (a_)*64);                   \
        gll16(As_ + (size_t)(128 + a_)*KD,  da_ + (128 + a_)*64); } while (0)
#define STG_A1(d, kt) do {                                                    \
        const f16* As_ = aT + (size_t)(kt) * 64; f16* da_ = &shA[d][0];       \
        gll16(As_ + (size_t)(64 + a_)*KD,   da_ + (64 + a_)*64);              \
        gll16(As_ + (size_t)(192 + a_)*KD,  da_ + (192 + a_)*64); } while (0)
#define STG_B0(d, kt) do {                                                    \
        const f16* Bs_ = bT + (size_t)(kt) * 64; f16* db_ = &shB[d][0];       \
        gll16(Bs_ + (size_t)(bq_)*KD,       db_ + (bq_)*64);                  \
        gll16(Bs_ + (size_t)(128 + bq_)*KD, db_ + (128 + bq_)*64); } while (0)
#define STG_B1(d, kt) do {                                                    \
        const f16* Bs_ = bT + (size_t)(kt) * 64; f16* db_ = &shB[d][0];       \
        gll16(Bs_ + (size_t)(32 + bq_)*KD,  db_ + (32 + bq_)*64);             \
        gll16(Bs_ + (size_t)(160 + bq_)*KD, db_ + (160 + bq_)*64); } while (0)

    f16x8 af[2][2][4];     // [mh][kk][i]
    f16x8 bf[2][2][2];     // [nh][kk][j]
    f32x4 acc[8][4] = {};

#define LDA(mh)                                                               \
    _Pragma("unroll") for (int kk_ = 0; kk_ < 2; ++kk_)                       \
    _Pragma("unroll") for (int i_ = 0; i_ < 4; ++i_)                          \
        af[mh][kk_][i_] = *(const f16x8*)(sAc +                               \
            (wr * 128 + (mh) * 64 + i_ * 16 + fr) * 128 +                     \
            (((kk_ << 6) | kb) ^ sw));

#define LDB(nh)                                                               \
    _Pragma("unroll") for (int kk_ = 0; kk_ < 2; ++kk_)                       \
    _Pragma("unroll") for (int j_ = 0; j_ < 2; ++j_)                          \
        bf[nh][kk_][j_] = *(const f16x8*)(sBc +                               \
            (wc * 64 + (nh) * 32 + j_ * 16 + fr) * 128 +                      \
            (((kk_ << 6) | kb) ^ sw));

#define MM(mh, nh)                                                            \
    __builtin_amdgcn_s_setprio(1);                                            \
    _Pragma("unroll") for (int kk_ = 0; kk_ < 2; ++kk_)                       \
    _Pragma("unroll") for (int i_ = 0; i_ < 4; ++i_)                          \
    _Pragma("unroll") for (int j_ = 0; j_ < 2; ++j_)                          \
        acc[(mh) * 4 + i_][(nh) * 2 + j_] =                                   \
            MFMA16(af[mh][kk_][i_], bf[nh][kk_][j_],                          \
                   acc[(mh) * 4 + i_][(nh) * 2 + j_]);                        \
    __builtin_amdgcn_s_setprio(0);

    constexpr int NT = KD / 64;

    // prologue: tile 0 fully staged (8 glls), then 3 halves of tile 1.
    STG_A0(0, 0); STG_B0(0, 0); STG_B1(0, 0); STG_A1(0, 0);
    VMC(4);
    STG_A0(1, 1); STG_B0(1, 1); STG_B1(1, 1);
    VMC(6);                  // tile 0 landed; A0,B0,B1(1) in flight (6 glls)
    BAR();

    for (int ti = 0; ti < NT; ++ti) {
        const int c = ti & 1;
        const char* sAc = (const char*)&shA[c][0];
        const char* sBc = (const char*)&shB[c][0];
        const bool p1 = (ti + 1 < NT);   // stage A1(ti+1)
        const bool p2 = (ti + 2 < NT);   // stage A0/B0/B1(ti+2) -> buf c
        // phi1: reads af0+bf0 (12); stage A1(t+1)
        LDA(0); LDB(0);
        if (p1) STG_A1(c ^ 1, ti + 1);
        LGKM(8);
        BAR(); LGKM(0); MM(0, 0); BAR();
        // phi2: reads bf1 (4); stage A0(t+2)
        LDB(1);
        if (p2) STG_A0(c, ti + 2);
        BAR(); LGKM(0); MM(0, 1); BAR();
        // phi3: reads af1 (8); stage B0(t+2)
        LDA(1);
        if (p2) STG_B0(c, ti + 2);
        BAR(); LGKM(0); MM(1, 1); BAR();
        // phi4: no reads; stage B1(t+2); ONE gate per tile
        if (p2) { STG_B1(c, ti + 2); VMC(6); }   // retires all of tile t+1
        else if (p1) VMC(0);                     // peel: drain A1(NT-1)
        BAR(); MM(1, 0); BAR();
    }

    const int fc = lane & 15, rq = (lane >> 4) * 4;

    if constexpr (EPI == 2) {
        BAR();   // reuse shA as part[256][4]
        float* part = (float*)&shA[0][0];
        f16* Sp = (f16*)C0 + (size_t)z * strC;
#pragma unroll
        for (int mi = 0; mi < 8; ++mi)
#pragma unroll
            for (int r = 0; r < 4; ++r) {
                const int rl = wr * 128 + mi * 16 + rq + r;
                float ps = 0.f;
#pragma unroll
                for (int nj = 0; nj < 4; ++nj) {
                    const int col = bn + wc * 64 + nj * 16 + fc;
                    f16 eh = (f16)__expf(acc[mi][nj][r]);
                    ps += (float)eh;
                    Sp[(size_t)(bm + rl) * ldc + col] = eh;
                }
#pragma unroll
                for (int o = 1; o < 16; o <<= 1) ps += __shfl_xor(ps, o);
                if (fc == 0) part[rl * 4 + wc] = ps;
            }
        BAR();
        if (t < 256) {
            const float4 p4 = *(const float4*)(part + t * 4);
            aux[((size_t)z * 2048 + bm + t) * 8 + by] = p4.x + p4.y + p4.z + p4.w;
        }
        return;
    }

#pragma unroll
    for (int nj = 0; nj < 4; ++nj) {
        const int col = bn + wc * 64 + nj * 16 + fc;
        float bv_ = 0.f;
        if constexpr (EPI == 0) bv_ = b0[col];
        if constexpr (EPI == 1) bv_ = (col < 1024) ? b0[col] : b1[col - 1024];
#pragma unroll
        for (int mi = 0; mi < 8; ++mi) {
            if constexpr (EPI == 1) {
                if (col >= 1024) {
                    const int rowb = bm + wr * 128 + mi * 16 + rq;
                    f16x4 q;
#pragma unroll
                    for (int r = 0; r < 4; ++r) q[r] = (f16)(acc[mi][nj][r] + bv_);
                    f16* Cp = (f16*)C1 + (size_t)(rowb >> 11) * 2048 * 1024 +
                              (size_t)(col - 1024) * 2048;
                    *(f16x4*)&Cp[rowb & 2047] = q;
                    continue;
                }
            }
#pragma unroll
            for (int r = 0; r < 4; ++r) {
                const int row = bm + wr * 128 + mi * 16 + rq + r;
                float v = acc[mi][nj][r];
                if constexpr (EPI == 0) v = (v + bv_) * scale;
                if constexpr (EPI == 1) v = v + bv_;
                if constexpr (EPI == 3) v *= aux[(size_t)z * 2048 + row];
                if constexpr (EPI == 0) {
                    ((f16*)C0)[(size_t)row * ldc + col] = (f16)v;
                } else if constexpr (EPI == 1) {
                    ((f16*)C0)[(size_t)row * 1024 + col] = (f16)v;
                } else {
                    ((float*)C0 + (size_t)z * strC)[(size_t)row * ldc + col] = v;
                }
            }
        }
    }
#undef STG_A0
#undef STG_A1
#undef STG_B0
#undef STG_B1
#undef LDA
#undef LDB
#undef MM
}

// ---------------------------------------------------------------------------
// rowinv: inv[q] = 1 / sum_{j<8} part[q*8+j]
// ---------------------------------------------------------------------------
__global__ __launch_bounds__(256) void rowinv_k(
    const float* __restrict__ part, float* __restrict__ inv)
{
    const int q = blockIdx.x * 256 + threadIdx.x;
    const float4* p = (const float4*)(part + (size_t)q * 8);
    const float4 a = p[0], b = p[1];
    inv[q] = 1.0f / (a.x + a.y + a.z + a.w + b.x + b.y + b.z + b.w);
}

// ---------------------------------------------------------------------------
extern "C" void kernel_launch(void* const* d_in, const int* in_sizes, int n_in,
                              void* d_out, int out_size, void* d_ws, size_t ws_size,
                              hipStream_t stream)
{
    const float* x   = (const float*)d_in[0];
    const float* enc = (const float*)d_in[1];
    const float* Wq  = (const float*)d_in[2];
    const float* bq  = (const float*)d_in[3];
    const float* Wk  = (const float*)d_in[4];
    const float* bk  = (const float*)d_in[5];
    const float* Wv  = (const float*)d_in[6];
    const float* bv  = (const float*)d_in[7];

    const size_t TOK = (size_t)16 * 2048;            // 32768 rows
    f16* Qh = (f16*)d_ws;                            // 64 MiB
    f16* Kh = Qh + TOK * 1024;                       // 64 MiB
    f16* Vt = Kh + TOK * 1024;                       // 64 MiB (V^T [16][1024][2048])
    f16* Wt = Vt + TOK * 1024;                       // 6 MiB ([Wq;Wk;Wv] f16, K-major)
    f16* S  = Wt + (size_t)3 * 1024 * 1024;          // 128 MiB (exp scores)
    f16* Xh = S;                                     // x in f16 (dead after proj)
    f16* Eh = S + TOK * 1024;                        // enc in f16 (dead after proj)
    float* Ppart = (float*)Wt;                       // 1 MiB (Wt dead after proj)
    float* Rinv  = Ppart + TOK * 8;                  // 128 KiB

    // 0) inputs -> f16
    cvt_f16<<<16384, 256, 0, stream>>>(x,   Xh);
    cvt_f16<<<16384, 256, 0, stream>>>(enc, Eh);

    // 1) weights -> f16, transposed
    prep_weights<<<dim3(32, 32, 3), 256, 0, stream>>>(Wq, Wk, Wv, Wt);

    // 2) Q projection (1/32 score scale folded in)
    gemm8<1024, 0><<<512, 512, 0, stream>>>(
        Xh, Wt, bq, nullptr, 0.03125f, Qh, nullptr, nullptr,
        0, 0, 0, 1024, 128, 4);

    // 3) fused K|V projection (B rows = [Wk;Wv]); V written transposed
    gemm8<1024, 1><<<1024, 512, 0, stream>>>(
        Eh, Wt + (size_t)1024 * 1024, bk, bv, 1.0f, Kh, Vt, nullptr,
        0, 0, 0, 1024, 128, 8);

    // 4) S = exp(Q K^T) + per-row partial sums (no max needed: |s| <~ 6)
    gemm8<1024, 2><<<1024, 512, 0, stream>>>(
        Qh, Kh, nullptr, nullptr, 1.0f, S, nullptr, Ppart,
        (size_t)2048 * 1024, (size_t)2048 * 1024, (size_t)2048 * 2048, 2048, 8, 8);

    // 5) row-sum inverse
    rowinv_k<<<128, 256, 0, stream>>>(Ppart, Rinv);

    // 6) H = (exp S) V * rowinv -> fp32 out
    gemm8<2048, 3><<<512, 512, 0, stream>>>(
        S, Vt, nullptr, nullptr, 1.0f, d_out, nullptr, Rinv,
        (size_t)2048 * 2048, (size_t)1024 * 2048, (size_t)2048 * 1024, 1024, 8, 4);
}

// Round 10
// 651.562 us; speedup vs baseline: 1.0851x; 1.0851x over previous
//
#include <hip/hip_runtime.h>

typedef _Float16 f16;
typedef __attribute__((ext_vector_type(4))) _Float16 f16x4;
typedef __attribute__((ext_vector_type(8))) _Float16 f16x8;
typedef __attribute__((ext_vector_type(4))) float f32x4;

#define MFMA16(a, b, c) __builtin_amdgcn_mfma_f32_16x16x32_f16(a, b, c, 0, 0, 0)

__device__ __forceinline__ void gll16(const void* g, void* l) {
    __builtin_amdgcn_global_load_lds(
        (const __attribute__((address_space(1))) unsigned int*)g,
        (__attribute__((address_space(3))) unsigned int*)l, 16, 0, 0);
}

#define BAR() __builtin_amdgcn_s_barrier()
#define LGKM(n) do { asm volatile("s_waitcnt lgkmcnt(" #n ")" ::: "memory"); \
                     __builtin_amdgcn_sched_barrier(0); } while (0)
#define VMC(n)  do { asm volatile("s_waitcnt vmcnt(" #n ")" ::: "memory"); \
                     __builtin_amdgcn_sched_barrier(0); } while (0)

// ---------------------------------------------------------------------------
// fp32 -> f16 convert
// ---------------------------------------------------------------------------
__global__ __launch_bounds__(256) void cvt_f16(
    const float* __restrict__ in, f16* __restrict__ out)
{
    const size_t i = ((size_t)blockIdx.x * 256 + threadIdx.x) * 8;
    float4 a = *(const float4*)(in + i);
    float4 b = *(const float4*)(in + i + 4);
    f16x8 o;
    o[0] = (f16)a.x; o[1] = (f16)a.y; o[2] = (f16)a.z; o[3] = (f16)a.w;
    o[4] = (f16)b.x; o[5] = (f16)b.y; o[6] = (f16)b.z; o[7] = (f16)b.w;
    *(f16x8*)(out + i) = o;
}

// ---------------------------------------------------------------------------
// Weight prep: W fp32 [K=1024][N=1024] -> Wt f16 [N][K]
// ---------------------------------------------------------------------------
__global__ __launch_bounds__(256) void prep_weights(
    const float* __restrict__ Wq, const float* __restrict__ Wk,
    const float* __restrict__ Wv, f16* __restrict__ Wt)
{
    __shared__ float tile[32][33];
    const float* W = blockIdx.z == 0 ? Wq : (blockIdx.z == 1 ? Wk : Wv);
    f16* dst = Wt + (size_t)blockIdx.z * 1024 * 1024;
    const int tx = threadIdx.x & 31, ty = threadIdx.x >> 5;
    const int n0 = blockIdx.x * 32, k0 = blockIdx.y * 32;
#pragma unroll
    for (int i = 0; i < 4; i++)
        tile[ty + i * 8][tx] = W[(size_t)(k0 + ty + i * 8) * 1024 + n0 + tx];
    __syncthreads();
#pragma unroll
    for (int i = 0; i < 4; i++)
        dst[(size_t)(n0 + ty + i * 8) * 1024 + k0 + tx] = (f16)tile[tx][ty + i * 8];
}

// ---------------------------------------------------------------------------
// 256x256 GEMM, champion 4-phase/tile schedule (657us bench) with zero
// per-tile address VALU: 2-tile-unrolled K-loop (compile-time buffer ids),
// precomputed swizzled LDS byte-offsets, properly-hoisted stage pointers
// (aT0 = aT + a_*KD, bT0 = bT + bq_*KD  — r9's bug was dropping these).
// EPI: 0 = bias+scale -> f16 (Q proj)
//      1 = fused K|V proj: cols<1024 -> C0 (Kh), cols>=1024 -> C1 transposed (Vt)
//      2 = exp -> f16 S + per-row partial sums -> aux (QK^T)
//      3 = multiply by aux[row] -> f32 (PV)
// ---------------------------------------------------------------------------
template <int KD, int EPI>
__global__ __launch_bounds__(512, 2) void gemm8(
    const f16* __restrict__ Ab, const f16* __restrict__ Bb,
    const float* __restrict__ b0, const float* __restrict__ b1, float scale,
    void* __restrict__ C0, void* __restrict__ C1, float* __restrict__ aux,
    size_t strA, size_t strB, size_t strC, int ldc, int nbx, int nby)
{
    __shared__ f16 shA[2 * 256 * 64];   // buffer d at d*16384 elems (d*32768 B)
    __shared__ f16 shB[2 * 256 * 64];

    int id = blockIdx.x;
    {
        const int chunk = (int)gridDim.x >> 3;
        id = (id & 7) * chunk + (id >> 3);
    }
    const int by = id % nby;
    const int r2 = id / nby;
    const int bx = r2 % nbx;
    const int z  = r2 / nbx;
    const int bm = bx * 256, bn = by * 256;

    const f16* A = Ab + (size_t)z * strA;
    const f16* B = Bb + (size_t)z * strB;

    const int t = threadIdx.x, lane = t & 63, wid = t >> 6;
    const int wr = wid >> 2, wc = wid & 3;
    const int fr = lane & 15, kb = (lane >> 4) * 16;
    const int sw = (fr & 7) << 4;

    const int lsr = lane >> 3;
    const int lsc = ((lane & 7) * 16) ^ (lsr << 4);
    const int a_  = wid * 8;
    const int bq_ = (wid >> 2) * 64 + (wid & 3) * 8;
    // per-thread, per-wave hoisted global staging bases (include row offsets!)
    const f16* aT0 = A + (size_t)(bm + lsr + 0) * KD + (lsc >> 1) + (size_t)a_ * KD;
    const f16* bT0 = B + (size_t)(bn + lsr + 0) * KD + (lsc >> 1) + (size_t)bq_ * KD;

    // precomputed swizzled fragment-read byte offsets (per thread, K-invariant)
    const char* Ab_ = (const char*)shA;
    const char* Bb_ = (const char*)shB;
    const int aoffk0 = (wr * 128 + fr) * 128 + (kb ^ sw);
    const int aoffk1 = (wr * 128 + fr) * 128 + ((64 | kb) ^ sw);
    const int boffk0 = (wc * 64 + fr) * 128 + (kb ^ sw);
    const int boffk1 = (wc * 64 + fr) * 128 + ((64 | kb) ^ sw);

// stage units (2 glls each); d is a compile-time literal in every expansion.
// Sources: aT0 + {0,64,128,192}*KD, bT0 + {0,32,128,160}*KD  (+ kt*64).
#define STG_A0(d, kt) do {                                                    \
        const f16* As_ = aT0 + (size_t)(kt) * 64;                             \
        gll16(As_,                      shA + (d) * 16384 + (a_)*64);         \
        gll16(As_ + (size_t)128 * KD,   shA + (d) * 16384 + (128 + a_)*64); } while (0)
#define STG_A1(d, kt) do {                                                    \
        const f16* As_ = aT0 + (size_t)(kt) * 64;                             \
        gll16(As_ + (size_t)64 * KD,    shA + (d) * 16384 + (64 + a_)*64);    \
        gll16(As_ + (size_t)192 * KD,   shA + (d) * 16384 + (192 + a_)*64); } while (0)
#define STG_B0(d, kt) do {                                                    \
        const f16* Bs_ = bT0 + (size_t)(kt) * 64;                             \
        gll16(Bs_,                      shB + (d) * 16384 + (bq_)*64);        \
        gll16(Bs_ + (size_t)128 * KD,   shB + (d) * 16384 + (128 + bq_)*64); } while (0)
#define STG_B1(d, kt) do {                                                    \
        const f16* Bs_ = bT0 + (size_t)(kt) * 64;                             \
        gll16(Bs_ + (size_t)32 * KD,    shB + (d) * 16384 + (32 + bq_)*64);   \
        gll16(Bs_ + (size_t)160 * KD,   shB + (d) * 16384 + (160 + bq_)*64); } while (0)

    f16x8 af[2][2][4];     // [mh][kk][i]
    f16x8 bf[2][2][2];     // [nh][kk][j]
    f32x4 acc[8][4] = {};

// fragment reads: base char* + precomputed reg offset + compile-time imm
#define LDA_(d, mh)                                                           \
    _Pragma("unroll") for (int i_ = 0; i_ < 4; ++i_) {                        \
        af[mh][0][i_] = *(const f16x8*)(Ab_ + (d) * 32768 + aoffk0 +          \
                                        ((mh) * 64 + i_ * 16) * 128);         \
        af[mh][1][i_] = *(const f16x8*)(Ab_ + (d) * 32768 + aoffk1 +          \
                                        ((mh) * 64 + i_ * 16) * 128);         \
    }
#define LDB_(d, nh)                                                           \
    _Pragma("unroll") for (int j_ = 0; j_ < 2; ++j_) {                        \
        bf[nh][0][j_] = *(const f16x8*)(Bb_ + (d) * 32768 + boffk0 +          \
                                        ((nh) * 32 + j_ * 16) * 128);         \
        bf[nh][1][j_] = *(const f16x8*)(Bb_ + (d) * 32768 + boffk1 +          \
                                        ((nh) * 32 + j_ * 16) * 128);         \
    }

#define MM(mh, nh)                                                            \
    __builtin_amdgcn_s_setprio(1);                                            \
    _Pragma("unroll") for (int kk_ = 0; kk_ < 2; ++kk_)                       \
    _Pragma("unroll") for (int i_ = 0; i_ < 4; ++i_)                          \
    _Pragma("unroll") for (int j_ = 0; j_ < 2; ++j_)                          \
        acc[(mh) * 4 + i_][(nh) * 2 + j_] =                                   \
            MFMA16(af[mh][kk_][i_], bf[nh][kk_][j_],                          \
                   acc[(mh) * 4 + i_][(nh) * 2 + j_]);                        \
    __builtin_amdgcn_s_setprio(0);

// full tile on buffer d (compile-time), staging tile kt+1 into buffer d^1
#define TILE_FULL(d, kt)                                                      \
    do {                                                                      \
        LDA_(d, 0); LDB_(d, 0);                                               \
        STG_A0((d) ^ 1, (kt) + 1); VMC(4);                                    \
        BAR(); LGKM(0); MM(0, 0); BAR();                                      \
        LDB_(d, 1);                                                           \
        STG_B0((d) ^ 1, (kt) + 1); VMC(4);                                    \
        BAR(); LGKM(0); MM(0, 1); BAR();                                      \
        LDA_(d, 1);                                                           \
        STG_B1((d) ^ 1, (kt) + 1);                                            \
        BAR(); LGKM(0); MM(1, 1); BAR();                                      \
        STG_A1((d) ^ 1, (kt) + 1); VMC(4);                                    \
        BAR(); MM(1, 0); BAR();                                               \
    } while (0)

// last tile on buffer d: no staging, drain gates
#define TILE_TAIL(d)                                                          \
    do {                                                                      \
        LDA_(d, 0); LDB_(d, 0);                                               \
        VMC(2);                                                               \
        BAR(); LGKM(0); MM(0, 0); BAR();                                      \
        LDB_(d, 1);                                                           \
        VMC(0);                                                               \
        BAR(); LGKM(0); MM(0, 1); BAR();                                      \
        LDA_(d, 1);                                                           \
        BAR(); LGKM(0); MM(1, 1); BAR();                                      \
        BAR(); MM(1, 0); BAR();                                               \
    } while (0)

    constexpr int NT = KD / 64;   // 16 or 32, always even

    // prologue: tile 0 fully staged; A0,B0 landed before first reads.
    STG_A0(0, 0); STG_B0(0, 0); STG_B1(0, 0); STG_A1(0, 0);
    VMC(4);
    BAR();

    for (int ti = 0; ti < NT - 2; ti += 2) {
        TILE_FULL(0, ti);
        TILE_FULL(1, ti + 1);
    }
    TILE_FULL(0, NT - 2);
    TILE_TAIL(1);

    const int fc = lane & 15, rq = (lane >> 4) * 4;

    if constexpr (EPI == 2) {
        BAR();   // reuse shA as part[256][4]
        float* part = (float*)shA;
        f16* Sp = (f16*)C0 + (size_t)z * strC;
#pragma unroll
        for (int mi = 0; mi < 8; ++mi)
#pragma unroll
            for (int r = 0; r < 4; ++r) {
                const int rl = wr * 128 + mi * 16 + rq + r;
                float ps = 0.f;
#pragma unroll
                for (int nj = 0; nj < 4; ++nj) {
                    const int col = bn + wc * 64 + nj * 16 + fc;
                    f16 eh = (f16)__expf(acc[mi][nj][r]);
                    ps += (float)eh;
                    Sp[(size_t)(bm + rl) * ldc + col] = eh;
                }
#pragma unroll
                for (int o = 1; o < 16; o <<= 1) ps += __shfl_xor(ps, o);
                if (fc == 0) part[rl * 4 + wc] = ps;
            }
        BAR();
        if (t < 256) {
            const float4 p4 = *(const float4*)(part + t * 4);
            aux[((size_t)z * 2048 + bm + t) * 8 + by] = p4.x + p4.y + p4.z + p4.w;
        }
        return;
    }

#pragma unroll
    for (int nj = 0; nj < 4; ++nj) {
        const int col = bn + wc * 64 + nj * 16 + fc;
        float bv_ = 0.f;
        if constexpr (EPI == 0) bv_ = b0[col];
        if constexpr (EPI == 1) bv_ = (col < 1024) ? b0[col] : b1[col - 1024];
#pragma unroll
        for (int mi = 0; mi < 8; ++mi) {
            if constexpr (EPI == 1) {
                if (col >= 1024) {
                    const int rowb = bm + wr * 128 + mi * 16 + rq;
                    f16x4 q;
#pragma unroll
                    for (int r = 0; r < 4; ++r) q[r] = (f16)(acc[mi][nj][r] + bv_);
                    f16* Cp = (f16*)C1 + (size_t)(rowb >> 11) * 2048 * 1024 +
                              (size_t)(col - 1024) * 2048;
                    *(f16x4*)&Cp[rowb & 2047] = q;
                    continue;
                }
            }
#pragma unroll
            for (int r = 0; r < 4; ++r) {
                const int row = bm + wr * 128 + mi * 16 + rq + r;
                float v = acc[mi][nj][r];
                if constexpr (EPI == 0) v = (v + bv_) * scale;
                if constexpr (EPI == 1) v = v + bv_;
                if constexpr (EPI == 3) v *= aux[(size_t)z * 2048 + row];
                if constexpr (EPI == 0) {
                    ((f16*)C0)[(size_t)row * ldc + col] = (f16)v;
                } else if constexpr (EPI == 1) {
                    ((f16*)C0)[(size_t)row * 1024 + col] = (f16)v;
                } else {
                    ((float*)C0 + (size_t)z * strC)[(size_t)row * ldc + col] = v;
                }
            }
        }
    }
#undef STG_A0
#undef STG_A1
#undef STG_B0
#undef STG_B1
#undef LDA_
#undef LDB_
#undef MM
#undef TILE_FULL
#undef TILE_TAIL
}

// ---------------------------------------------------------------------------
// rowinv: inv[q] = 1 / sum_{j<8} part[q*8+j]
// ---------------------------------------------------------------------------
__global__ __launch_bounds__(256) void rowinv_k(
    const float* __restrict__ part, float* __restrict__ inv)
{
    const int q = blockIdx.x * 256 + threadIdx.x;
    const float4* p = (const float4*)(part + (size_t)q * 8);
    const float4 a = p[0], b = p[1];
    inv[q] = 1.0f / (a.x + a.y + a.z + a.w + b.x + b.y + b.z + b.w);
}

// ---------------------------------------------------------------------------
extern "C" void kernel_launch(void* const* d_in, const int* in_sizes, int n_in,
                              void* d_out, int out_size, void* d_ws, size_t ws_size,
                              hipStream_t stream)
{
    const float* x   = (const float*)d_in[0];
    const float* enc = (const float*)d_in[1];
    const float* Wq  = (const float*)d_in[2];
    const float* bq  = (const float*)d_in[3];
    const float* Wk  = (const float*)d_in[4];
    const float* bk  = (const float*)d_in[5];
    const float* Wv  = (const float*)d_in[6];
    const float* bv  = (const float*)d_in[7];

    const size_t TOK = (size_t)16 * 2048;            // 32768 rows
    f16* Qh = (f16*)d_ws;                            // 64 MiB
    f16* Kh = Qh + TOK * 1024;                       // 64 MiB
    f16* Vt = Kh + TOK * 1024;                       // 64 MiB (V^T [16][1024][2048])
    f16* Wt = Vt + TOK * 1024;                       // 6 MiB ([Wq;Wk;Wv] f16, K-major)
    f16* S  = Wt + (size_t)3 * 1024 * 1024;          // 128 MiB (exp scores)
    f16* Xh = S;                                     // x in f16 (dead after proj)
    f16* Eh = S + TOK * 1024;                        // enc in f16 (dead after proj)
    float* Ppart = (float*)Wt;                       // 1 MiB (Wt dead after proj)
    float* Rinv  = Ppart + TOK * 8;                  // 128 KiB

    // 0) inputs -> f16
    cvt_f16<<<16384, 256, 0, stream>>>(x,   Xh);
    cvt_f16<<<16384, 256, 0, stream>>>(enc, Eh);

    // 1) weights -> f16, transposed
    prep_weights<<<dim3(32, 32, 3), 256, 0, stream>>>(Wq, Wk, Wv, Wt);

    // 2) Q projection (1/32 score scale folded in)
    gemm8<1024, 0><<<512, 512, 0, stream>>>(
        Xh, Wt, bq, nullptr, 0.03125f, Qh, nullptr, nullptr,
        0, 0, 0, 1024, 128, 4);

    // 3) fused K|V projection (B rows = [Wk;Wv]); V written transposed
    gemm8<1024, 1><<<1024, 512, 0, stream>>>(
        Eh, Wt + (size_t)1024 * 1024, bk, bv, 1.0f, Kh, Vt, nullptr,
        0, 0, 0, 1024, 128, 8);

    // 4) S = exp(Q K^T) + per-row partial sums (no max needed: |s| <~ 6)
    gemm8<1024, 2><<<1024, 512, 0, stream>>>(
        Qh, Kh, nullptr, nullptr, 1.0f, S, nullptr, Ppart,
        (size_t)2048 * 1024, (size_t)2048 * 1024, (size_t)2048 * 2048, 2048, 8, 8);

    // 5) row-sum inverse
    rowinv_k<<<128, 256, 0, stream>>>(Ppart, Rinv);

    // 6) H = (exp S) V * rowinv -> fp32 out
    gemm8<2048, 3><<<512, 512, 0, stream>>>(
        S, Vt, nullptr, nullptr, 1.0f, d_out, nullptr, Rinv,
        (size_t)2048 * 2048, (size_t)1024 * 2048, (size_t)2048 * 1024, 1024, 8, 4);
}